// Round 2
// baseline (15410.979 us; speedup 1.0000x reference)
//
#include <hip/hip_runtime.h>
#include <hip/hip_bf16.h>

#define T_STEPS 512
#define TS8     8192          // s16x8 chunks per t-slot: 8 groups * 16 ktiles * 64 lanes
#define TS_US   65536         // ushorts per t-slot (128KB)

typedef __attribute__((ext_vector_type(4))) float f32x4;
typedef __attribute__((ext_vector_type(8))) short s16x8;

// ---------- helpers ----------
__device__ __forceinline__ unsigned short f2bf(float f){
  unsigned int u = __float_as_uint(f);
  unsigned int r = (u + 0x7fffu + ((u >> 16) & 1u)) >> 16;
  return (unsigned short)r;
}
__device__ __forceinline__ float fsig(float x){
  return __builtin_amdgcn_rcpf(1.f + __expf(-x));
}
__device__ __forceinline__ float ftanh(float x){
  x = fminf(fmaxf(x, -15.f), 15.f);
  float a = __expf(2.f * x);
  return (a - 1.f) * __builtin_amdgcn_rcpf(a + 1.f);
}

// ---------- pack x into per-group MFMA A-fragment layout ----------
// xp layout: [t][g(8)][kt(16)][lane(64)][8] bf16.  A-frag: row = lane&15 (batch row
// within group), k = kt*32 + (lane>>4)*8 + e.
__global__ void k_pack_x(const float* __restrict__ x, unsigned short* __restrict__ xp){
  int t = blockIdx.x >> 3, g = blockIdx.x & 7;
  __shared__ unsigned short xs[16*520];
  int tid = threadIdx.x;
  for (int q = tid; q < 1024; q += 256){
    int rw = q >> 6, k8 = q & 63;
    const float* src = x + ((size_t)(g*16 + rw)*512 + t)*512 + k8*8;
    union { unsigned short u[8]; s16x8 v; } tmp;
#pragma unroll
    for (int e = 0; e < 8; e++) tmp.u[e] = f2bf(src[e]);
    *(s16x8*)&xs[rw*520 + k8*8] = tmp.v;
  }
  __syncthreads();
  for (int s = tid; s < 1024; s += 256){
    int kt = s >> 6, ln = s & 63;
    int rw2 = ln & 15, k0 = kt*32 + (ln >> 4)*8;
    s16x8 v = *(const s16x8*)&xs[rw2*520 + k0];
    ((s16x8*)xp)[(size_t)t*TS8 + (g*16 + kt)*64 + ln] = v;
  }
}

// ---------- pack layer-1 weights into B-fragment layout ----------
// wp layout: [r(32)][ch=kt*4+n (128)][lane(64)][8] bf16.
// B-frag: col = n*512 + r*16 + (lane&15), k = kt*32 + (lane>>4)*8 + e
// (kt<16 -> Wi row k; kt>=16 -> Wh row k-512)
__global__ void k_pack_w1(const float* __restrict__ Wi, const float* __restrict__ Wh,
                          const float* __restrict__ b, unsigned short* __restrict__ wp,
                          float* __restrict__ bias){
  int r = blockIdx.x, tid = threadIdx.x;
  int lane = tid & 63, u0 = tid >> 6;
  for (int ch = u0; ch < 128; ch += 4){
    int kt = ch >> 2, n = ch & 3;
    int col = n*512 + r*16 + (lane & 15);
    int kb = kt*32 + (lane >> 4)*8;
    union { unsigned short u[8]; s16x8 v; } tmp;
#pragma unroll
    for (int e = 0; e < 8; e++){
      int k = kb + e;
      float wv = (kt < 16) ? Wi[(size_t)k*2048 + col] : Wh[(size_t)(k-512)*2048 + col];
      tmp.u[e] = f2bf(wv);
    }
    ((s16x8*)wp)[((size_t)r*128 + ch)*64 + lane] = tmp.v;
  }
  if (tid < 64) bias[r*64 + tid] = b[(tid >> 4)*512 + r*16 + (tid & 15)];
}

// ---------- fold BN1 into Wi2, pack layer-2 weights, compute fused bias ----------
__global__ void k_fold2(const float* __restrict__ Wi2, const float* __restrict__ Wh2,
                        const float* __restrict__ b2, const float* __restrict__ gamma,
                        const float* __restrict__ beta, const float* __restrict__ stats,
                        unsigned short* __restrict__ wp, float* __restrict__ bias){
  __shared__ float a_s[512], c_s[512], red[256];
  int r = blockIdx.x, tid = threadIdx.x;
  for (int k = tid; k < 512; k += 256){
    float sm = 0.f, sq = 0.f;
#pragma unroll
    for (int g = 0; g < 8; g++){ sm += stats[(k*8+g)*2]; sq += stats[(k*8+g)*2+1]; }
    float mean = sm * (1.f/65536.f);
    float var  = sq * (1.f/65536.f) - mean*mean;
    float rr = rsqrtf(fmaxf(var, 0.f) + 1e-5f);
    float a = rr * gamma[k];
    a_s[k] = a; c_s[k] = beta[k] - mean*a;
  }
  __syncthreads();
  int lane = tid & 63, u0 = tid >> 6;
  for (int ch = u0; ch < 128; ch += 4){
    int kt = ch >> 2, n = ch & 3;
    int col = n*512 + r*16 + (lane & 15);
    int kb = kt*32 + (lane >> 4)*8;
    union { unsigned short u[8]; s16x8 v; } tmp;
#pragma unroll
    for (int e = 0; e < 8; e++){
      int k = kb + e;
      float wv = (kt < 16) ? a_s[k]*Wi2[(size_t)k*2048 + col]
                           : Wh2[(size_t)(k-512)*2048 + col];
      tmp.u[e] = f2bf(wv);
    }
    ((s16x8*)wp)[((size_t)r*128 + ch)*64 + lane] = tmp.v;
  }
  // bias2' = b2 + c_s @ Wi2 for this block's 64 cols
  int colj = tid >> 2, part = tid & 3;
  int n = colj >> 4, cl = colj & 15;
  int col = n*512 + r*16 + cl;
  float s = 0.f;
  for (int k = part*128; k < part*128 + 128; k++) s += c_s[k]*Wi2[(size_t)k*2048 + col];
  red[tid] = s;
  __syncthreads();
  if (part == 0)
    bias[r*64 + colj] = b2[col] + red[tid] + red[tid+1] + red[tid+2] + red[tid+3];
}

__global__ void k_reset(int* f1, int* f2){
  int t = threadIdx.x;
  if (t < 512){ f1[t] = 0; f2[t] = 0; }
}

__global__ void k_sentinel(float* out, int n, float v){
  int i = blockIdx.x * blockDim.x + threadIdx.x;
  if (i < n) out[i] = v;
}

// ---------- persistent group-local LSTM scan ----------
// 256 blocks x 512 threads. Group g = blockIdx&7 (XCD-aligned if %8 mapping holds),
// rank r = blockIdx>>3. Group owns batch rows [g*16, g*16+16); block owns h-cols
// [r*16, r*16+16) (= 64 z-cols, 4 gates x 16). Weights live in registers
// (16 B-frags/wave). Waves own disjoint K-slices; partial z summed in LDS.
template<int LAYER>
__global__ __launch_bounds__(512)
void k_scan(const unsigned short* __restrict__ xin, unsigned short* __restrict__ hex,
            const unsigned short* __restrict__ wp, const float* __restrict__ bias,
            int* __restrict__ flags, float* __restrict__ aux){
  __shared__ float zsum[4*16*17];
  __shared__ float blds[64];
  __shared__ unsigned short hst[256];
  int g = blockIdx.x & 7, r = blockIdx.x >> 3;
  int tid = threadIdx.x, w = tid >> 6, lane = tid & 63;

  // weight fragments -> registers: wave w owns ktiles {2w,2w+1,16+2w,17+2w}
  const s16x8* wpv = (const s16x8*)wp + (size_t)r*128*64;
  s16x8 B[4][4];
  {
    int kts[4] = {2*w, 2*w+1, 16+2*w, 17+2*w};
#pragma unroll
    for (int ki = 0; ki < 4; ki++)
#pragma unroll
      for (int n = 0; n < 4; n++)
        B[ki][n] = wpv[((size_t)kts[ki]*4 + n)*64 + lane];
  }
  if (tid < 64) blds[tid] = bias[r*64 + tid];

  int row = tid & 15, cl = (tid >> 4) & 15;      // gate-thread ownership (tid<256)
  int rw = (lane >> 4)*4, cw = lane & 15;        // MFMA C-frag position
  float c = 0.f, s1 = 0.f, s2 = 0.f;

  const s16x8* xv = (const s16x8*)xin;
  s16x8* hv = (s16x8*)hex;

  for (int t = 0; t < T_STEPS; t++){
    for (int i = tid; i < 4*16*17; i += 512) zsum[i] = 0.f;

    f32x4 acc[4];
#pragma unroll
    for (int n = 0; n < 4; n++) acc[n] = (f32x4){0.f,0.f,0.f,0.f};

    // X-phase (no dependence on h_{t-1})
    {
      const s16x8* ax = xv + (size_t)t*TS8 + (g*16 + 2*w)*64 + lane;
      s16x8 a0 = ax[0], a1 = ax[64];
#pragma unroll
      for (int n = 0; n < 4; n++) acc[n] = __builtin_amdgcn_mfma_f32_16x16x32_bf16(a0, B[0][n], acc[n], 0,0,0);
#pragma unroll
      for (int n = 0; n < 4; n++) acc[n] = __builtin_amdgcn_mfma_f32_16x16x32_bf16(a1, B[1][n], acc[n], 0,0,0);
    }
    // wait for the whole group to have published h_{t-1}
    if (t > 0 && w == 0){
      int bail = 0;
      for (;;){
        int mn = 0x7fffffff;
        if (lane < 8){
#pragma unroll
          for (int j = 0; j < 4; j++){
            int f = __hip_atomic_load(&flags[g*64 + lane*4 + j], __ATOMIC_RELAXED, __HIP_MEMORY_SCOPE_AGENT);
            mn = min(mn, f);
          }
        }
        if (__all(mn >= t)) break;
        __builtin_amdgcn_s_sleep(2);
        if (++bail > (1<<21)) break;   // safety: never hang the harness
      }
    }
    __syncthreads();
    if (t > 0){
      const s16x8* ah = hv + (size_t)(t-1)*TS8 + (g*16 + 2*w)*64 + lane;
      s16x8 h0 = ah[0], h1 = ah[64];
#pragma unroll
      for (int n = 0; n < 4; n++) acc[n] = __builtin_amdgcn_mfma_f32_16x16x32_bf16(h0, B[2][n], acc[n], 0,0,0);
#pragma unroll
      for (int n = 0; n < 4; n++) acc[n] = __builtin_amdgcn_mfma_f32_16x16x32_bf16(h1, B[3][n], acc[n], 0,0,0);
    }
    // reduce partial z across waves
#pragma unroll
    for (int n = 0; n < 4; n++)
#pragma unroll
      for (int i = 0; i < 4; i++)
        atomicAdd(&zsum[(n*16 + rw + i)*17 + cw], acc[n][i]);
    __syncthreads();

    if (tid < 256){
      float zi = zsum[(     row)*17 + cl] + blds[     cl];
      float zf = zsum[(16 + row)*17 + cl] + blds[16 + cl];
      float zg = zsum[(32 + row)*17 + cl] + blds[32 + cl];
      float zo = zsum[(48 + row)*17 + cl] + blds[48 + cl];
      float gi = fsig(zi), gf = fsig(zf), go = fsig(zo), gg = ftanh(zg);
      c = gf*c + gi*gg;
      float h = go * ftanh(c);
      if (LAYER == 1){ s1 += h; s2 += h*h; }
      hst[row*16 + cl] = f2bf(h);
      if (LAYER == 2 && t == T_STEPS-1) aux[(g*16 + row)*512 + r*16 + cl] = h;
    }
    __syncthreads();

    if (tid < 32){
      // one coalesced 512B chunk: block r = lanes [(r&1)*32, +32) of ktile r>>1
      s16x8 v = *(const s16x8*)&hst[(tid & 15)*16 + (tid >> 4)*8];
      hv[(size_t)t*TS8 + (g*16 + (r >> 1))*64 + (r & 1)*32 + tid] = v;
      if (tid == 0)
        __hip_atomic_store(&flags[g*64 + r], t+1, __ATOMIC_RELEASE, __HIP_MEMORY_SCOPE_AGENT);
    }
  }

  if (LAYER == 1 && tid < 256){
    // reduce stats over the group's 16 rows (cluster of 16 consecutive lanes)
    s1 += __shfl_down(s1, 8); s2 += __shfl_down(s2, 8);
    s1 += __shfl_down(s1, 4); s2 += __shfl_down(s2, 4);
    s1 += __shfl_down(s1, 2); s2 += __shfl_down(s2, 2);
    s1 += __shfl_down(s1, 1); s2 += __shfl_down(s2, 1);
    if ((tid & 15) == 0){
      int ch = r*16 + cl;
      aux[(ch*8 + g)*2]     = s1;
      aux[(ch*8 + g)*2 + 1] = s2;
    }
  }
}

// ---------- BN2 + dense head ----------
__global__ __launch_bounds__(512)
void k_epilogue(const float* __restrict__ h2,
                const float* __restrict__ g2, const float* __restrict__ be2,
                const float* __restrict__ Wd1, const float* __restrict__ bd1,
                const float* __restrict__ Wd2, const float* __restrict__ bd2,
                float* __restrict__ out){
  __shared__ float mu[512], rs[512], bb[512];
  __shared__ float t16[128*16];
  int tid = threadIdx.x;
  {
    float s = 0.f, q = 0.f;
    for (int r = 0; r < 128; r++){ float v = h2[r*512 + tid]; s += v; q += v*v; }
    float m = s * (1.f/128.f);
    float var = q * (1.f/128.f) - m*m;
    mu[tid] = m;
    rs[tid] = rsqrtf(fmaxf(var,0.f) + 1e-5f) * g2[tid];
    bb[tid] = be2[tid];
  }
  __syncthreads();
  for (int task = tid; task < 2048; task += 512){
    int b = task >> 4, u = task & 15;
    float acc = bd1[u];
    for (int k = 0; k < 512; k++){
      float hn = (h2[b*512 + k] - mu[k]) * rs[k] + bb[k];
      acc += hn * Wd1[k*16 + u];
    }
    t16[task] = tanhf(acc);
  }
  __syncthreads();
  if (tid < 128){
    float acc = bd2[0];
#pragma unroll
    for (int u = 0; u < 16; u++) acc += t16[tid*16 + u] * Wd2[u];
    out[tid] = acc;
  }
}

extern "C" void kernel_launch(void* const* d_in, const int* in_sizes, int n_in,
                              void* d_out, int out_size, void* d_ws, size_t ws_size,
                              hipStream_t stream){
  const float* x    = (const float*)d_in[0];
  const float* Wi1  = (const float*)d_in[1];
  const float* Wh1  = (const float*)d_in[2];
  const float* b1   = (const float*)d_in[3];
  const float* Wi2  = (const float*)d_in[4];
  const float* Wh2  = (const float*)d_in[5];
  const float* b2   = (const float*)d_in[6];
  const float* g1   = (const float*)d_in[7];
  const float* be1  = (const float*)d_in[8];
  const float* g2   = (const float*)d_in[9];
  const float* be2  = (const float*)d_in[10];
  const float* Wd1  = (const float*)d_in[11];
  const float* bd1  = (const float*)d_in[12];
  const float* Wd2  = (const float*)d_in[13];
  const float* bd2  = (const float*)d_in[14];
  float* out = (float*)d_out;

  char* ws = (char*)d_ws;
  size_t off = 0;
  auto alloc = [&](size_t bytes)->void*{
    void* pp = ws + off; off += (bytes + 255) & ~(size_t)255; return pp;
  };
  unsigned short* xpacked = (unsigned short*)alloc((size_t)512*TS_US*2);  // 64 MiB
  unsigned short* S       = (unsigned short*)alloc((size_t)514*TS_US*2);  // 64.25 MiB
  unsigned short* w1p     = (unsigned short*)alloc((size_t)32*128*64*8*2);
  unsigned short* w2p     = (unsigned short*)alloc((size_t)32*128*64*8*2);
  float* bias1  = (float*)alloc(2048*4);
  float* bias2  = (float*)alloc(2048*4);
  float* stats1 = (float*)alloc((size_t)512*8*2*4);
  int*   flags1 = (int*)alloc(2048);
  int*   flags2 = (int*)alloc(2048);
  float* h2last = (float*)alloc((size_t)128*512*4);

  if (off > ws_size){
    k_sentinel<<<1, 256, 0, stream>>>(out, out_size, (float)(ws_size >> 20));
    return;
  }

  unsigned short* S2 = S + (size_t)2*TS_US;   // write slot t -> S[t+2]

  k_reset<<<1, 512, 0, stream>>>(flags1, flags2);
  k_pack_x<<<4096, 256, 0, stream>>>(x, xpacked);
  k_pack_w1<<<32, 256, 0, stream>>>(Wi1, Wh1, b1, w1p, bias1);
  k_scan<1><<<256, 512, 0, stream>>>(xpacked, S2, w1p, bias1, flags1, stats1);
  k_fold2<<<32, 256, 0, stream>>>(Wi2, Wh2, b2, g1, be1, stats1, w2p, bias2);
  k_scan<2><<<256, 512, 0, stream>>>(S2, xpacked, w2p, bias2, flags2, h2last);
  k_epilogue<<<1, 512, 0, stream>>>(h2last, g2, be2, Wd1, bd1, Wd2, bd2, out);
}

// Round 3
// 2574.592 us; speedup vs baseline: 5.9858x; 5.9858x over previous
//
#include <hip/hip_runtime.h>
#include <hip/hip_bf16.h>

#define T_STEPS 512
#define TS8     8192          // s16x8 chunks per t-slot: 8 groups * 16 ktiles * 64 lanes
#define TS_US   65536         // ushorts per t-slot (128KB)

typedef __attribute__((ext_vector_type(4))) float f32x4;
typedef __attribute__((ext_vector_type(8))) short s16x8;

// ---------- helpers ----------
__device__ __forceinline__ unsigned short f2bf(float f){
  unsigned int u = __float_as_uint(f);
  unsigned int r = (u + 0x7fffu + ((u >> 16) & 1u)) >> 16;
  return (unsigned short)r;
}
__device__ __forceinline__ float fsig(float x){
  return __builtin_amdgcn_rcpf(1.f + __expf(-x));
}
__device__ __forceinline__ float ftanh(float x){
  x = fminf(fmaxf(x, -15.f), 15.f);
  float a = __expf(2.f * x);
  return (a - 1.f) * __builtin_amdgcn_rcpf(a + 1.f);
}

// ---------- pack x into per-group MFMA A-fragment layout ----------
// xp layout: [t][g(8)][kt(16)][lane(64)][8] bf16.  A-frag: row = lane&15 (batch row
// within group), k = kt*32 + (lane>>4)*8 + e.
__global__ void k_pack_x(const float* __restrict__ x, unsigned short* __restrict__ xp){
  int t = blockIdx.x >> 3, g = blockIdx.x & 7;
  __shared__ unsigned short xs[16*520];
  int tid = threadIdx.x;
  for (int q = tid; q < 1024; q += 256){
    int rw = q >> 6, k8 = q & 63;
    const float* src = x + ((size_t)(g*16 + rw)*512 + t)*512 + k8*8;
    union { unsigned short u[8]; s16x8 v; } tmp;
#pragma unroll
    for (int e = 0; e < 8; e++) tmp.u[e] = f2bf(src[e]);
    *(s16x8*)&xs[rw*520 + k8*8] = tmp.v;
  }
  __syncthreads();
  for (int s = tid; s < 1024; s += 256){
    int kt = s >> 6, ln = s & 63;
    int rw2 = ln & 15, k0 = kt*32 + (ln >> 4)*8;
    s16x8 v = *(const s16x8*)&xs[rw2*520 + k0];
    ((s16x8*)xp)[(size_t)t*TS8 + (g*16 + kt)*64 + ln] = v;
  }
}

// ---------- pack layer-1 weights into B-fragment layout ----------
// wp layout: [r(32)][ch=kt*4+n (128)][lane(64)][8] bf16.
// B-frag: col = n*512 + r*16 + (lane&15), k = kt*32 + (lane>>4)*8 + e
// (kt<16 -> Wi row k; kt>=16 -> Wh row k-512)
__global__ void k_pack_w1(const float* __restrict__ Wi, const float* __restrict__ Wh,
                          const float* __restrict__ b, unsigned short* __restrict__ wp,
                          float* __restrict__ bias){
  int r = blockIdx.x, tid = threadIdx.x;
  int lane = tid & 63, u0 = tid >> 6;
  for (int ch = u0; ch < 128; ch += 4){
    int kt = ch >> 2, n = ch & 3;
    int col = n*512 + r*16 + (lane & 15);
    int kb = kt*32 + (lane >> 4)*8;
    union { unsigned short u[8]; s16x8 v; } tmp;
#pragma unroll
    for (int e = 0; e < 8; e++){
      int k = kb + e;
      float wv = (kt < 16) ? Wi[(size_t)k*2048 + col] : Wh[(size_t)(k-512)*2048 + col];
      tmp.u[e] = f2bf(wv);
    }
    ((s16x8*)wp)[((size_t)r*128 + ch)*64 + lane] = tmp.v;
  }
  if (tid < 64) bias[r*64 + tid] = b[(tid >> 4)*512 + r*16 + (tid & 15)];
}

// ---------- fold BN1 into Wi2, pack layer-2 weights, compute fused bias ----------
__global__ void k_fold2(const float* __restrict__ Wi2, const float* __restrict__ Wh2,
                        const float* __restrict__ b2, const float* __restrict__ gamma,
                        const float* __restrict__ beta, const float* __restrict__ stats,
                        unsigned short* __restrict__ wp, float* __restrict__ bias){
  __shared__ float a_s[512], c_s[512], red[256];
  int r = blockIdx.x, tid = threadIdx.x;
  for (int k = tid; k < 512; k += 256){
    float sm = 0.f, sq = 0.f;
#pragma unroll
    for (int g = 0; g < 8; g++){ sm += stats[(k*8+g)*2]; sq += stats[(k*8+g)*2+1]; }
    float mean = sm * (1.f/65536.f);
    float var  = sq * (1.f/65536.f) - mean*mean;
    float rr = rsqrtf(fmaxf(var, 0.f) + 1e-5f);
    float a = rr * gamma[k];
    a_s[k] = a; c_s[k] = beta[k] - mean*a;
  }
  __syncthreads();
  int lane = tid & 63, u0 = tid >> 6;
  for (int ch = u0; ch < 128; ch += 4){
    int kt = ch >> 2, n = ch & 3;
    int col = n*512 + r*16 + (lane & 15);
    int kb = kt*32 + (lane >> 4)*8;
    union { unsigned short u[8]; s16x8 v; } tmp;
#pragma unroll
    for (int e = 0; e < 8; e++){
      int k = kb + e;
      float wv = (kt < 16) ? a_s[k]*Wi2[(size_t)k*2048 + col]
                           : Wh2[(size_t)(k-512)*2048 + col];
      tmp.u[e] = f2bf(wv);
    }
    ((s16x8*)wp)[((size_t)r*128 + ch)*64 + lane] = tmp.v;
  }
  // bias2' = b2 + c_s @ Wi2 for this block's 64 cols
  int colj = tid >> 2, part = tid & 3;
  int n = colj >> 4, cl = colj & 15;
  int col = n*512 + r*16 + cl;
  float s = 0.f;
  for (int k = part*128; k < part*128 + 128; k++) s += c_s[k]*Wi2[(size_t)k*2048 + col];
  red[tid] = s;
  __syncthreads();
  if (part == 0)
    bias[r*64 + colj] = b2[col] + red[tid] + red[tid+1] + red[tid+2] + red[tid+3];
}

__global__ void k_reset(int* f1, int* f2){
  int t = threadIdx.x;
  if (t < 512){ f1[t] = 0; f2[t] = 0; }
}

__global__ void k_sentinel(float* out, int n, float v){
  int i = blockIdx.x * blockDim.x + threadIdx.x;
  if (i < n) out[i] = v;
}

// ---------- persistent group-local LSTM scan ----------
// 256 blocks x 256 threads (4 waves). Group g = blockIdx&7, rank r = blockIdx>>3.
// Group owns batch rows [g*16,g*16+16); block owns h-cols [r*16,r*16+16)
// (= 64 z-cols). Weights in registers (32 B-frags/wave). Wave w owns K-slice
// ktiles {4w..4w+3} (x) and {16+4w..16+4w+3} (h); partial z via LDS zones.
// Sync: per-group counter, relaxed agent atomics only (NO release fences ->
// no per-step L2 writeback). h published via relaxed agent dword stores (sc1,
// performed at coherence point); readers' plain loads are safe because each
// t-slot address is written-once and first read only after the counter gate.
template<int LAYER>
__global__ __launch_bounds__(256, 1)
void k_scan(const unsigned short* __restrict__ xin, unsigned short* __restrict__ hex,
            const unsigned short* __restrict__ wp, const float* __restrict__ bias,
            int* __restrict__ cnt, float* __restrict__ aux){
  __shared__ __align__(16) float zs[4*64*20];   // [w][col(64)][row pitch 20]
  __shared__ float blds[64];
  __shared__ unsigned short hst[256];
  int g = blockIdx.x & 7, r = blockIdx.x >> 3;
  int tid = threadIdx.x, w = tid >> 6, lane = tid & 63;
  int* gcnt = cnt + g*64;

  // weight fragments -> registers
  const s16x8* wpv = (const s16x8*)wp + (size_t)r*128*64;
  s16x8 B[8][4];
#pragma unroll
  for (int ki = 0; ki < 8; ki++){
    int kt = (ki < 4) ? (4*w + ki) : (12 + 4*w + ki);   // ki>=4 -> 16 + 4w + (ki-4)
#pragma unroll
    for (int n = 0; n < 4; n++)
      B[ki][n] = wpv[((size_t)kt*4 + n)*64 + lane];
  }
  if (tid < 64) blds[tid] = bias[r*64 + tid];
  __syncthreads();

  int row = tid & 15, cl = (tid >> 4) & 15;   // gate ownership (all 256 threads)
  int rw = (lane >> 4)*4, cw = lane & 15;     // MFMA C-frag position
  float c = 0.f, s1 = 0.f, s2 = 0.f;

  const s16x8* xv = (const s16x8*)xin;
  const s16x8* hvr = (const s16x8*)hex;
  unsigned int* hvw = (unsigned int*)hex;

  // prefetch x fragments for t=0
  s16x8 xa[4];
  {
    const s16x8* ax = xv + (g*16 + 4*w)*64 + lane;
#pragma unroll
    for (int i = 0; i < 4; i++) xa[i] = ax[i*64];
  }

  for (int t = 0; t < T_STEPS; t++){
    f32x4 acc[4];
#pragma unroll
    for (int n = 0; n < 4; n++) acc[n] = (f32x4){0.f,0.f,0.f,0.f};
    // X phase (independent of recurrence)
#pragma unroll
    for (int ki = 0; ki < 4; ki++)
#pragma unroll
      for (int n = 0; n < 4; n++)
        acc[n] = __builtin_amdgcn_mfma_f32_16x16x32_bf16(xa[ki], B[ki][n], acc[n], 0,0,0);
    // prefetch next step's x while we wait
    if (t + 1 < T_STEPS){
      const s16x8* ax = xv + (size_t)(t+1)*TS8 + (g*16 + 4*w)*64 + lane;
#pragma unroll
      for (int i = 0; i < 4; i++) xa[i] = ax[i*64];
    }
    if (t > 0){
      int target = 32*t, bail = 0;
      while (__hip_atomic_load(gcnt, __ATOMIC_RELAXED, __HIP_MEMORY_SCOPE_AGENT) < target){
        __builtin_amdgcn_s_sleep(1);
        if (++bail > (1<<17)) break;   // safety valve
      }
      asm volatile("" ::: "memory");   // no hoisting of h loads above the gate
      const s16x8* ah = hvr + (size_t)(t-1)*TS8 + (g*16 + 4*w)*64 + lane;
      s16x8 h0 = ah[0], h1 = ah[64], h2 = ah[128], h3 = ah[192];
#pragma unroll
      for (int n = 0; n < 4; n++) acc[n] = __builtin_amdgcn_mfma_f32_16x16x32_bf16(h0, B[4][n], acc[n], 0,0,0);
#pragma unroll
      for (int n = 0; n < 4; n++) acc[n] = __builtin_amdgcn_mfma_f32_16x16x32_bf16(h1, B[5][n], acc[n], 0,0,0);
#pragma unroll
      for (int n = 0; n < 4; n++) acc[n] = __builtin_amdgcn_mfma_f32_16x16x32_bf16(h2, B[6][n], acc[n], 0,0,0);
#pragma unroll
      for (int n = 0; n < 4; n++) acc[n] = __builtin_amdgcn_mfma_f32_16x16x32_bf16(h3, B[7][n], acc[n], 0,0,0);
    }
    // zone stores (vector b128, pitch 20 floats -> 2-way banks, free)
#pragma unroll
    for (int n = 0; n < 4; n++)
      *(f32x4*)&zs[(w*64 + n*16 + cw)*20 + rw] = acc[n];
    __syncthreads();
    // gate math: thread owns (row, hcol = r*16+cl)
    {
      float z4[4];
#pragma unroll
      for (int n = 0; n < 4; n++){
        float s = zs[(      n*16 + cl)*20 + row]
                + zs[( 64 + n*16 + cl)*20 + row]
                + zs[(128 + n*16 + cl)*20 + row]
                + zs[(192 + n*16 + cl)*20 + row];
        z4[n] = s + blds[n*16 + cl];
      }
      float gi = fsig(z4[0]), gf = fsig(z4[1]), gg = ftanh(z4[2]), go = fsig(z4[3]);
      c = gf*c + gi*gg;
      float h = go * ftanh(c);
      if (LAYER == 1){ s1 += h; s2 += h*h; }
      hst[row*16 + cl] = f2bf(h);
      if (LAYER == 2 && t == T_STEPS-1) aux[(g*16 + row)*512 + r*16 + cl] = h;
    }
    __syncthreads();
    // publish h: relaxed agent dword stores (coherence point, no fence)
    if (tid < 32){
      const unsigned int* hu = (const unsigned int*)hst;
      int boff = (lane & 15)*8 + (lane >> 4)*4;
      size_t ci = ((size_t)t*TS8 + (g*16 + (r >> 1))*64 + (r & 1)*32 + lane)*4;
#pragma unroll
      for (int j = 0; j < 4; j++)
        __hip_atomic_store(&hvw[ci + j], hu[boff + j], __ATOMIC_RELAXED, __HIP_MEMORY_SCOPE_AGENT);
    }
    if (tid == 0){
      asm volatile("s_waitcnt vmcnt(0)" ::: "memory");   // h stores acked (same wave)
      __hip_atomic_fetch_add(gcnt, 1, __ATOMIC_RELAXED, __HIP_MEMORY_SCOPE_AGENT);
    }
  }

  if (LAYER == 1){
    // reduce stats over the group's 16 rows (16-lane clusters)
    s1 += __shfl_down(s1, 8); s2 += __shfl_down(s2, 8);
    s1 += __shfl_down(s1, 4); s2 += __shfl_down(s2, 4);
    s1 += __shfl_down(s1, 2); s2 += __shfl_down(s2, 2);
    s1 += __shfl_down(s1, 1); s2 += __shfl_down(s2, 1);
    if ((tid & 15) == 0){
      int ch = r*16 + cl;
      aux[(ch*8 + g)*2]     = s1;
      aux[(ch*8 + g)*2 + 1] = s2;
    }
  }
}

// ---------- BN2 + dense head ----------
__global__ __launch_bounds__(512)
void k_epilogue(const float* __restrict__ h2,
                const float* __restrict__ g2, const float* __restrict__ be2,
                const float* __restrict__ Wd1, const float* __restrict__ bd1,
                const float* __restrict__ Wd2, const float* __restrict__ bd2,
                float* __restrict__ out){
  __shared__ float mu[512], rs[512], bb[512];
  __shared__ float t16[128*16];
  int tid = threadIdx.x;
  {
    float s = 0.f, q = 0.f;
    for (int r = 0; r < 128; r++){ float v = h2[r*512 + tid]; s += v; q += v*v; }
    float m = s * (1.f/128.f);
    float var = q * (1.f/128.f) - m*m;
    mu[tid] = m;
    rs[tid] = rsqrtf(fmaxf(var,0.f) + 1e-5f) * g2[tid];
    bb[tid] = be2[tid];
  }
  __syncthreads();
  for (int task = tid; task < 2048; task += 512){
    int b = task >> 4, u = task & 15;
    float acc = bd1[u];
    for (int k = 0; k < 512; k++){
      float hn = (h2[b*512 + k] - mu[k]) * rs[k] + bb[k];
      acc += hn * Wd1[k*16 + u];
    }
    t16[task] = tanhf(acc);
  }
  __syncthreads();
  if (tid < 128){
    float acc = bd2[0];
#pragma unroll
    for (int u = 0; u < 16; u++) acc += t16[tid*16 + u] * Wd2[u];
    out[tid] = acc;
  }
}

extern "C" void kernel_launch(void* const* d_in, const int* in_sizes, int n_in,
                              void* d_out, int out_size, void* d_ws, size_t ws_size,
                              hipStream_t stream){
  const float* x    = (const float*)d_in[0];
  const float* Wi1  = (const float*)d_in[1];
  const float* Wh1  = (const float*)d_in[2];
  const float* b1   = (const float*)d_in[3];
  const float* Wi2  = (const float*)d_in[4];
  const float* Wh2  = (const float*)d_in[5];
  const float* b2   = (const float*)d_in[6];
  const float* g1   = (const float*)d_in[7];
  const float* be1  = (const float*)d_in[8];
  const float* g2   = (const float*)d_in[9];
  const float* be2  = (const float*)d_in[10];
  const float* Wd1  = (const float*)d_in[11];
  const float* bd1  = (const float*)d_in[12];
  const float* Wd2  = (const float*)d_in[13];
  const float* bd2  = (const float*)d_in[14];
  float* out = (float*)d_out;

  char* ws = (char*)d_ws;
  size_t off = 0;
  auto alloc = [&](size_t bytes)->void*{
    void* pp = ws + off; off += (bytes + 255) & ~(size_t)255; return pp;
  };
  unsigned short* xpacked = (unsigned short*)alloc((size_t)512*TS_US*2);  // 64 MiB
  unsigned short* S       = (unsigned short*)alloc((size_t)514*TS_US*2);  // 64.25 MiB
  unsigned short* w1p     = (unsigned short*)alloc((size_t)32*128*64*8*2);
  unsigned short* w2p     = (unsigned short*)alloc((size_t)32*128*64*8*2);
  float* bias1  = (float*)alloc(2048*4);
  float* bias2  = (float*)alloc(2048*4);
  float* stats1 = (float*)alloc((size_t)512*8*2*4);
  int*   cnt1   = (int*)alloc(2048);
  int*   cnt2   = (int*)alloc(2048);
  float* h2last = (float*)alloc((size_t)128*512*4);

  if (off > ws_size){
    k_sentinel<<<1, 256, 0, stream>>>(out, out_size, (float)(ws_size >> 20));
    return;
  }

  unsigned short* S2 = S + (size_t)2*TS_US;

  k_reset<<<1, 512, 0, stream>>>(cnt1, cnt2);
  k_pack_x<<<4096, 256, 0, stream>>>(x, xpacked);
  k_pack_w1<<<32, 256, 0, stream>>>(Wi1, Wh1, b1, w1p, bias1);
  k_scan<1><<<256, 256, 0, stream>>>(xpacked, S2, w1p, bias1, cnt1, stats1);
  k_fold2<<<32, 256, 0, stream>>>(Wi2, Wh2, b2, g1, be1, stats1, w2p, bias2);
  k_scan<2><<<256, 256, 0, stream>>>(S2, xpacked, w2p, bias2, cnt2, h2last);
  k_epilogue<<<1, 512, 0, stream>>>(h2last, g2, be2, Wd1, bd1, Wd2, bd2, out);
}

// Round 4
// 2072.922 us; speedup vs baseline: 7.4344x; 1.2420x over previous
//
#include <hip/hip_runtime.h>
#include <hip/hip_bf16.h>

#define T_STEPS 512
#define TS8     8192          // s16x8 chunks per t-slot: 8 groups * 16 ktiles * 64 lanes
#define TS_US   65536         // ushorts per t-slot (128KB)

typedef __attribute__((ext_vector_type(4))) float f32x4;
typedef __attribute__((ext_vector_type(8))) short s16x8;

// ---------- helpers ----------
__device__ __forceinline__ unsigned short f2bf(float f){
  unsigned int u = __float_as_uint(f);
  unsigned int r = (u + 0x7fffu + ((u >> 16) & 1u)) >> 16;
  return (unsigned short)r;
}
__device__ __forceinline__ float fsig(float x){
  return __builtin_amdgcn_rcpf(1.f + __expf(-x));
}
__device__ __forceinline__ float ftanh(float x){
  x = fminf(fmaxf(x, -15.f), 15.f);
  float a = __expf(2.f * x);
  return (a - 1.f) * __builtin_amdgcn_rcpf(a + 1.f);
}

// ---------- pack x into per-group MFMA A-fragment layout ----------
__global__ void k_pack_x(const float* __restrict__ x, unsigned short* __restrict__ xp){
  int t = blockIdx.x >> 3, g = blockIdx.x & 7;
  __shared__ unsigned short xs[16*520];
  int tid = threadIdx.x;
  for (int q = tid; q < 1024; q += 256){
    int rw = q >> 6, k8 = q & 63;
    const float* src = x + ((size_t)(g*16 + rw)*512 + t)*512 + k8*8;
    union { unsigned short u[8]; s16x8 v; } tmp;
#pragma unroll
    for (int e = 0; e < 8; e++) tmp.u[e] = f2bf(src[e]);
    *(s16x8*)&xs[rw*520 + k8*8] = tmp.v;
  }
  __syncthreads();
  for (int s = tid; s < 1024; s += 256){
    int kt = s >> 6, ln = s & 63;
    int rw2 = ln & 15, k0 = kt*32 + (ln >> 4)*8;
    s16x8 v = *(const s16x8*)&xs[rw2*520 + k0];
    ((s16x8*)xp)[(size_t)t*TS8 + (g*16 + kt)*64 + ln] = v;
  }
}

// ---------- pack layer-1 weights into B-fragment layout ----------
__global__ void k_pack_w1(const float* __restrict__ Wi, const float* __restrict__ Wh,
                          const float* __restrict__ b, unsigned short* __restrict__ wp,
                          float* __restrict__ bias){
  int r = blockIdx.x, tid = threadIdx.x;
  int lane = tid & 63, u0 = tid >> 6;
  for (int ch = u0; ch < 128; ch += 4){
    int kt = ch >> 2, n = ch & 3;
    int col = n*512 + r*16 + (lane & 15);
    int kb = kt*32 + (lane >> 4)*8;
    union { unsigned short u[8]; s16x8 v; } tmp;
#pragma unroll
    for (int e = 0; e < 8; e++){
      int k = kb + e;
      float wv = (kt < 16) ? Wi[(size_t)k*2048 + col] : Wh[(size_t)(k-512)*2048 + col];
      tmp.u[e] = f2bf(wv);
    }
    ((s16x8*)wp)[((size_t)r*128 + ch)*64 + lane] = tmp.v;
  }
  if (tid < 64) bias[r*64 + tid] = b[(tid >> 4)*512 + r*16 + (tid & 15)];
}

// ---------- fold BN1 into Wi2, pack layer-2 weights, fused bias ----------
__global__ void k_fold2(const float* __restrict__ Wi2, const float* __restrict__ Wh2,
                        const float* __restrict__ b2, const float* __restrict__ gamma,
                        const float* __restrict__ beta, const float* __restrict__ stats,
                        unsigned short* __restrict__ wp, float* __restrict__ bias){
  __shared__ float a_s[512], c_s[512], red[256];
  int r = blockIdx.x, tid = threadIdx.x;
  for (int k = tid; k < 512; k += 256){
    float sm = 0.f, sq = 0.f;
#pragma unroll
    for (int g = 0; g < 8; g++){ sm += stats[(k*8+g)*2]; sq += stats[(k*8+g)*2+1]; }
    float mean = sm * (1.f/65536.f);
    float var  = sq * (1.f/65536.f) - mean*mean;
    float rr = rsqrtf(fmaxf(var, 0.f) + 1e-5f);
    float a = rr * gamma[k];
    a_s[k] = a; c_s[k] = beta[k] - mean*a;
  }
  __syncthreads();
  int lane = tid & 63, u0 = tid >> 6;
  for (int ch = u0; ch < 128; ch += 4){
    int kt = ch >> 2, n = ch & 3;
    int col = n*512 + r*16 + (lane & 15);
    int kb = kt*32 + (lane >> 4)*8;
    union { unsigned short u[8]; s16x8 v; } tmp;
#pragma unroll
    for (int e = 0; e < 8; e++){
      int k = kb + e;
      float wv = (kt < 16) ? a_s[k]*Wi2[(size_t)k*2048 + col]
                           : Wh2[(size_t)(k-512)*2048 + col];
      tmp.u[e] = f2bf(wv);
    }
    ((s16x8*)wp)[((size_t)r*128 + ch)*64 + lane] = tmp.v;
  }
  int colj = tid >> 2, part = tid & 3;
  int n = colj >> 4, cl = colj & 15;
  int col = n*512 + r*16 + cl;
  float s = 0.f;
  for (int k = part*128; k < part*128 + 128; k++) s += c_s[k]*Wi2[(size_t)k*2048 + col];
  red[tid] = s;
  __syncthreads();
  if (part == 0)
    bias[r*64 + colj] = b2[col] + red[tid] + red[tid+1] + red[tid+2] + red[tid+3];
}

__global__ void k_reset(int* f1, int* f2, int* x1, int* x2){
  int t = threadIdx.x;
  for (int i = t; i < 4096; i += 1024){ f1[i] = 0; f2[i] = 0; }
  if (t < 256){ x1[t] = 0; x2[t] = 0; }
}

__global__ void k_sentinel(float* out, int n, float v){
  int i = blockIdx.x * blockDim.x + threadIdx.x;
  if (i < n) out[i] = v;
}

// ---------- persistent group-local LSTM scan ----------
// 256 blocks x 256 threads (4 waves). Group g = blockIdx&7, rank r = blockIdx>>3.
// Group owns batch rows [g*16,g*16+16); block owns h-cols [r*16,r*16+16).
// Weights in registers. Wave w owns ktiles {4w..4w+3} of x and of h.
// Sync: per-rank-per-wave flags on separate 64B lines, plain atomic STORES
// (no RMW -> no CP serialization). h data: if the whole group verifiably sits
// on one XCD (HW_REG_XCC_ID handshake), plain stores/loads meeting in the
// XCD-local L2; else agent-relaxed atomic dword stores at the coherence point
// (round-3-proven fallback). Flags always agent-scope at CP.
template<int LAYER>
__global__ __launch_bounds__(256, 1)
void k_scan(const unsigned short* __restrict__ xin, unsigned short* __restrict__ hex,
            const unsigned short* __restrict__ wp, const float* __restrict__ bias,
            int* __restrict__ flags, int* __restrict__ xmap, float* __restrict__ aux){
  __shared__ __align__(16) float zs[2][4*64*20];   // double-buffered zones
  __shared__ float blds[64];
  int g = blockIdx.x & 7, r = blockIdx.x >> 3;
  int tid = threadIdx.x, w = tid >> 6, lane = tid & 63;

  // weight fragments -> registers
  const s16x8* wpv = (const s16x8*)wp + (size_t)r*128*64;
  s16x8 B[8][4];
#pragma unroll
  for (int ki = 0; ki < 8; ki++){
    int kt = (ki < 4) ? (4*w + ki) : (12 + 4*w + ki);
#pragma unroll
    for (int n = 0; n < 4; n++)
      B[ki][n] = wpv[((size_t)kt*4 + n)*64 + lane];
  }
  if (tid < 64) blds[tid] = bias[r*64 + tid];

  // ---- XCD uniformity handshake (G16-safe fast path) ----
  int myx;
  asm volatile("s_getreg_b32 %0, hwreg(HW_REG_XCC_ID)" : "=s"(myx));
  if (tid == 0)
    __hip_atomic_store(&xmap[g*32 + r], (myx & 0xff) + 1, __ATOMIC_RELAXED, __HIP_MEMORY_SCOPE_AGENT);
  int xv, hb = 0;
  for (;;){
    xv = __hip_atomic_load(&xmap[g*32 + (lane & 31)], __ATOMIC_RELAXED, __HIP_MEMORY_SCOPE_AGENT);
    if (__all(xv != 0)) break;
    __builtin_amdgcn_s_sleep(2);
    if (++hb > (1<<18)) break;
  }
  int xv0 = __builtin_amdgcn_readfirstlane(xv);
  bool fastp = __all(xv != 0 && xv == xv0) != 0;
  __syncthreads();

  int row = tid & 15, cl = (tid >> 4) & 15;   // gate ownership
  int rw = (lane >> 4)*4, cw = lane & 15;     // MFMA C-frag position
  float c = 0.f, s1 = 0.f, s2 = 0.f;

  // publish constants: thread (row, hcol=r*16+cl) -> frag ushort address
  int lane_c = row + 16*((r & 1)*2 + (cl >> 3));
  size_t du_off = ((((size_t)(g*16 + (r >> 1))*64 + lane_c)*8) + (cl & 7)) >> 1;
  int* myflag = flags + (g*32 + r)*16 + w;
  const int* fb = flags + (g*32 + (lane & 31))*16 + (lane >> 5)*2;

  const s16x8* xv8 = (const s16x8*)xin;
  const s16x8* hvr = (const s16x8*)hex;
  unsigned int* hvw = (unsigned int*)hex;

  // prefetch x fragments for t=0
  s16x8 xa[4];
  {
    const s16x8* ax = xv8 + (g*16 + 4*w)*64 + lane;
#pragma unroll
    for (int i = 0; i < 4; i++) xa[i] = ax[i*64];
  }

  for (int t = 0; t < T_STEPS; t++){
    f32x4 acc[4];
#pragma unroll
    for (int n = 0; n < 4; n++) acc[n] = (f32x4){0.f,0.f,0.f,0.f};
    // X phase (independent of recurrence)
#pragma unroll
    for (int ki = 0; ki < 4; ki++)
#pragma unroll
      for (int n = 0; n < 4; n++)
        acc[n] = __builtin_amdgcn_mfma_f32_16x16x32_bf16(xa[ki], B[ki][n], acc[n], 0,0,0);
    // prefetch next step's x while waiting
    if (t + 1 < T_STEPS){
      const s16x8* ax = xv8 + (size_t)(t+1)*TS8 + (g*16 + 4*w)*64 + lane;
#pragma unroll
      for (int i = 0; i < 4; i++) xa[i] = ax[i*64];
    }
    if (t > 0){
      // poll 128 flags spread over 32 lines (each wave independently)
      int bail = 0;
      for (;;){
        int f0 = __hip_atomic_load(fb,   __ATOMIC_RELAXED, __HIP_MEMORY_SCOPE_AGENT);
        int f1 = __hip_atomic_load(fb+1, __ATOMIC_RELAXED, __HIP_MEMORY_SCOPE_AGENT);
        if (__all(min(f0, f1) >= t)) break;
        __builtin_amdgcn_s_sleep(2);
        if (++bail > (1<<17)) break;   // safety valve
      }
      asm volatile("" ::: "memory");
      const s16x8* ah = hvr + (size_t)(t-1)*TS8 + (g*16 + 4*w)*64 + lane;
      s16x8 h0 = ah[0], h1 = ah[64], h2 = ah[128], h3 = ah[192];
#pragma unroll
      for (int n = 0; n < 4; n++) acc[n] = __builtin_amdgcn_mfma_f32_16x16x32_bf16(h0, B[4][n], acc[n], 0,0,0);
#pragma unroll
      for (int n = 0; n < 4; n++) acc[n] = __builtin_amdgcn_mfma_f32_16x16x32_bf16(h1, B[5][n], acc[n], 0,0,0);
#pragma unroll
      for (int n = 0; n < 4; n++) acc[n] = __builtin_amdgcn_mfma_f32_16x16x32_bf16(h2, B[6][n], acc[n], 0,0,0);
#pragma unroll
      for (int n = 0; n < 4; n++) acc[n] = __builtin_amdgcn_mfma_f32_16x16x32_bf16(h3, B[7][n], acc[n], 0,0,0);
    }
    // zone stores (double-buffered; pitch 20 floats)
    float* zb = zs[t & 1];
#pragma unroll
    for (int n = 0; n < 4; n++)
      *(f32x4*)&zb[(w*64 + n*16 + cw)*20 + rw] = acc[n];
    __syncthreads();
    // gate math: thread owns (row, hcol = r*16+cl)
    float z4[4];
#pragma unroll
    for (int n = 0; n < 4; n++){
      z4[n] = zb[(      n*16 + cl)*20 + row]
            + zb[( 64 + n*16 + cl)*20 + row]
            + zb[(128 + n*16 + cl)*20 + row]
            + zb[(192 + n*16 + cl)*20 + row]
            + blds[n*16 + cl];
    }
    float gi = fsig(z4[0]), gf = fsig(z4[1]), gg = ftanh(z4[2]), go = fsig(z4[3]);
    c = gf*c + gi*gg;
    float h = go * ftanh(c);
    if (LAYER == 1){ s1 += h; s2 += h*h; }
    if (LAYER == 2 && t == T_STEPS-1) aux[(g*16 + row)*512 + r*16 + cl] = h;
    // publish h: pair (cl, cl+1) into one dword; lanes with even cl store
    unsigned hv = f2bf(h);
    unsigned w32 = hv | (((unsigned)__shfl_down((int)hv, 16)) << 16);
    if (((lane >> 4) & 1) == 0){
      unsigned int* dst = hvw + ((size_t)t*(TS_US/2) + du_off);
      if (fastp) *dst = w32;                     // XCD-local L2 meet point
      else __hip_atomic_store(dst, w32, __ATOMIC_RELAXED, __HIP_MEMORY_SCOPE_AGENT);
    }
    asm volatile("s_waitcnt vmcnt(0)" ::: "memory");   // wave's h stores acked
    if (lane == 0)
      __hip_atomic_store(myflag, t+1, __ATOMIC_RELAXED, __HIP_MEMORY_SCOPE_AGENT);
  }

  if (LAYER == 1){
    s1 += __shfl_down(s1, 8); s2 += __shfl_down(s2, 8);
    s1 += __shfl_down(s1, 4); s2 += __shfl_down(s2, 4);
    s1 += __shfl_down(s1, 2); s2 += __shfl_down(s2, 2);
    s1 += __shfl_down(s1, 1); s2 += __shfl_down(s2, 1);
    if ((tid & 15) == 0){
      int ch = r*16 + cl;
      aux[(ch*8 + g)*2]     = s1;
      aux[(ch*8 + g)*2 + 1] = s2;
    }
  }
}

// ---------- BN2 + dense head ----------
__global__ __launch_bounds__(512)
void k_epilogue(const float* __restrict__ h2,
                const float* __restrict__ g2, const float* __restrict__ be2,
                const float* __restrict__ Wd1, const float* __restrict__ bd1,
                const float* __restrict__ Wd2, const float* __restrict__ bd2,
                float* __restrict__ out){
  __shared__ float mu[512], rs[512], bb[512];
  __shared__ float t16[128*16];
  int tid = threadIdx.x;
  {
    float s = 0.f, q = 0.f;
    for (int r = 0; r < 128; r++){ float v = h2[r*512 + tid]; s += v; q += v*v; }
    float m = s * (1.f/128.f);
    float var = q * (1.f/128.f) - m*m;
    mu[tid] = m;
    rs[tid] = rsqrtf(fmaxf(var,0.f) + 1e-5f) * g2[tid];
    bb[tid] = be2[tid];
  }
  __syncthreads();
  for (int task = tid; task < 2048; task += 512){
    int b = task >> 4, u = task & 15;
    float acc = bd1[u];
    for (int k = 0; k < 512; k++){
      float hn = (h2[b*512 + k] - mu[k]) * rs[k] + bb[k];
      acc += hn * Wd1[k*16 + u];
    }
    t16[task] = tanhf(acc);
  }
  __syncthreads();
  if (tid < 128){
    float acc = bd2[0];
#pragma unroll
    for (int u = 0; u < 16; u++) acc += t16[tid*16 + u] * Wd2[u];
    out[tid] = acc;
  }
}

extern "C" void kernel_launch(void* const* d_in, const int* in_sizes, int n_in,
                              void* d_out, int out_size, void* d_ws, size_t ws_size,
                              hipStream_t stream){
  const float* x    = (const float*)d_in[0];
  const float* Wi1  = (const float*)d_in[1];
  const float* Wh1  = (const float*)d_in[2];
  const float* b1   = (const float*)d_in[3];
  const float* Wi2  = (const float*)d_in[4];
  const float* Wh2  = (const float*)d_in[5];
  const float* b2   = (const float*)d_in[6];
  const float* g1   = (const float*)d_in[7];
  const float* be1  = (const float*)d_in[8];
  const float* g2   = (const float*)d_in[9];
  const float* be2  = (const float*)d_in[10];
  const float* Wd1  = (const float*)d_in[11];
  const float* bd1  = (const float*)d_in[12];
  const float* Wd2  = (const float*)d_in[13];
  const float* bd2  = (const float*)d_in[14];
  float* out = (float*)d_out;

  char* ws = (char*)d_ws;
  size_t off = 0;
  auto alloc = [&](size_t bytes)->void*{
    void* pp = ws + off; off += (bytes + 255) & ~(size_t)255; return pp;
  };
  unsigned short* xpacked = (unsigned short*)alloc((size_t)512*TS_US*2);  // 64 MiB
  unsigned short* S       = (unsigned short*)alloc((size_t)514*TS_US*2);  // 64.25 MiB
  unsigned short* w1p     = (unsigned short*)alloc((size_t)32*128*64*8*2);
  unsigned short* w2p     = (unsigned short*)alloc((size_t)32*128*64*8*2);
  float* bias1  = (float*)alloc(2048*4);
  float* bias2  = (float*)alloc(2048*4);
  float* stats1 = (float*)alloc((size_t)512*8*2*4);
  int*   flags1 = (int*)alloc(4096*4);
  int*   flags2 = (int*)alloc(4096*4);
  int*   xmap1  = (int*)alloc(1024);
  int*   xmap2  = (int*)alloc(1024);
  float* h2last = (float*)alloc((size_t)128*512*4);

  if (off > ws_size){
    k_sentinel<<<1, 256, 0, stream>>>(out, out_size, (float)(ws_size >> 20));
    return;
  }

  unsigned short* S2 = S + (size_t)2*TS_US;

  k_reset<<<1, 1024, 0, stream>>>(flags1, flags2, xmap1, xmap2);
  k_pack_x<<<4096, 256, 0, stream>>>(x, xpacked);
  k_pack_w1<<<32, 256, 0, stream>>>(Wi1, Wh1, b1, w1p, bias1);
  k_scan<1><<<256, 256, 0, stream>>>(xpacked, S2, w1p, bias1, flags1, xmap1, stats1);
  k_fold2<<<32, 256, 0, stream>>>(Wi2, Wh2, b2, g1, be1, stats1, w2p, bias2);
  k_scan<2><<<256, 256, 0, stream>>>(S2, xpacked, w2p, bias2, flags2, xmap2, h2last);
  k_epilogue<<<1, 512, 0, stream>>>(h2last, g2, be2, Wd1, bd1, Wd2, bd2, out);
}

// Round 6
// 2022.874 us; speedup vs baseline: 7.6184x; 1.0247x over previous
//
#include <hip/hip_runtime.h>
#include <hip/hip_bf16.h>

#define T_STEPS 512
#define TS8     8192          // s16x8 chunks per t-slot: 8 groups * 16 ktiles * 64 lanes
#define TS_US   65536         // ushorts per t-slot (128KB)

typedef __attribute__((ext_vector_type(4))) float f32x4;
typedef __attribute__((ext_vector_type(8))) short s16x8;

// ---------- helpers ----------
__device__ __forceinline__ unsigned short f2bf(float f){
  unsigned int u = __float_as_uint(f);
  unsigned int r = (u + 0x7fffu + ((u >> 16) & 1u)) >> 16;
  return (unsigned short)r;
}
__device__ __forceinline__ float fsig(float x){
  return __builtin_amdgcn_rcpf(1.f + __expf(-x));
}
__device__ __forceinline__ float ftanh(float x){
  x = fminf(fmaxf(x, -15.f), 15.f);
  float a = __expf(2.f * x);
  return (a - 1.f) * __builtin_amdgcn_rcpf(a + 1.f);
}

// ---------- pack x into per-group MFMA A-fragment layout ----------
__global__ void k_pack_x(const float* __restrict__ x, unsigned short* __restrict__ xp){
  int t = blockIdx.x >> 3, g = blockIdx.x & 7;
  __shared__ unsigned short xs[16*520];
  int tid = threadIdx.x;
  for (int q = tid; q < 1024; q += 256){
    int rw = q >> 6, k8 = q & 63;
    const float* src = x + ((size_t)(g*16 + rw)*512 + t)*512 + k8*8;
    union { unsigned short u[8]; s16x8 v; } tmp;
#pragma unroll
    for (int e = 0; e < 8; e++) tmp.u[e] = f2bf(src[e]);
    *(s16x8*)&xs[rw*520 + k8*8] = tmp.v;
  }
  __syncthreads();
  for (int s = tid; s < 1024; s += 256){
    int kt = s >> 6, ln = s & 63;
    int rw2 = ln & 15, k0 = kt*32 + (ln >> 4)*8;
    s16x8 v = *(const s16x8*)&xs[rw2*520 + k0];
    ((s16x8*)xp)[(size_t)t*TS8 + (g*16 + kt)*64 + ln] = v;
  }
}

// ---------- pack layer-1 weights into B-fragment layout ----------
__global__ void k_pack_w1(const float* __restrict__ Wi, const float* __restrict__ Wh,
                          const float* __restrict__ b, unsigned short* __restrict__ wp,
                          float* __restrict__ bias){
  int r = blockIdx.x, tid = threadIdx.x;
  int lane = tid & 63, u0 = tid >> 6;
  for (int ch = u0; ch < 128; ch += 4){
    int kt = ch >> 2, n = ch & 3;
    int col = n*512 + r*16 + (lane & 15);
    int kb = kt*32 + (lane >> 4)*8;
    union { unsigned short u[8]; s16x8 v; } tmp;
#pragma unroll
    for (int e = 0; e < 8; e++){
      int k = kb + e;
      float wv = (kt < 16) ? Wi[(size_t)k*2048 + col] : Wh[(size_t)(k-512)*2048 + col];
      tmp.u[e] = f2bf(wv);
    }
    ((s16x8*)wp)[((size_t)r*128 + ch)*64 + lane] = tmp.v;
  }
  if (tid < 64) bias[r*64 + tid] = b[(tid >> 4)*512 + r*16 + (tid & 15)];
}

// ---------- fold BN1 into Wi2, pack layer-2 weights, fused bias ----------
__global__ void k_fold2(const float* __restrict__ Wi2, const float* __restrict__ Wh2,
                        const float* __restrict__ b2, const float* __restrict__ gamma,
                        const float* __restrict__ beta, const float* __restrict__ stats,
                        unsigned short* __restrict__ wp, float* __restrict__ bias){
  __shared__ float a_s[512], c_s[512], red[256];
  int r = blockIdx.x, tid = threadIdx.x;
  for (int k = tid; k < 512; k += 256){
    float sm = 0.f, sq = 0.f;
#pragma unroll
    for (int g = 0; g < 8; g++){ sm += stats[(k*8+g)*2]; sq += stats[(k*8+g)*2+1]; }
    float mean = sm * (1.f/65536.f);
    float var  = sq * (1.f/65536.f) - mean*mean;
    float rr = rsqrtf(fmaxf(var, 0.f) + 1e-5f);
    float a = rr * gamma[k];
    a_s[k] = a; c_s[k] = beta[k] - mean*a;
  }
  __syncthreads();
  int lane = tid & 63, u0 = tid >> 6;
  for (int ch = u0; ch < 128; ch += 4){
    int kt = ch >> 2, n = ch & 3;
    int col = n*512 + r*16 + (lane & 15);
    int kb = kt*32 + (lane >> 4)*8;
    union { unsigned short u[8]; s16x8 v; } tmp;
#pragma unroll
    for (int e = 0; e < 8; e++){
      int k = kb + e;
      float wv = (kt < 16) ? a_s[k]*Wi2[(size_t)k*2048 + col]
                           : Wh2[(size_t)(k-512)*2048 + col];
      tmp.u[e] = f2bf(wv);
    }
    ((s16x8*)wp)[((size_t)r*128 + ch)*64 + lane] = tmp.v;
  }
  int colj = tid >> 2, part = tid & 3;
  int n = colj >> 4, cl = colj & 15;
  int col = n*512 + r*16 + cl;
  float s = 0.f;
  for (int k = part*128; k < part*128 + 128; k++) s += c_s[k]*Wi2[(size_t)k*2048 + col];
  red[tid] = s;
  __syncthreads();
  if (part == 0)
    bias[r*64 + colj] = b2[col] + red[tid] + red[tid+1] + red[tid+2] + red[tid+3];
}

__global__ void k_reset(int* f1, int* f2, int* x1, int* x2){
  int t = threadIdx.x;
  for (int i = t; i < 4096; i += 1024){ f1[i] = 0; f2[i] = 0; }
  if (t < 256){ x1[t] = 0; x2[t] = 0; }
}

__global__ void k_sentinel(float* out, int n, float v){
  int i = blockIdx.x * blockDim.x + threadIdx.x;
  if (i < n) out[i] = v;
}

// ---------- persistent group-local LSTM scan ----------
// 256 blocks x 256 threads (4 waves). Group g = blockIdx&7, rank r = blockIdx>>3.
// Group owns batch rows [g*16,g*16+16); block owns h-cols [r*16,r*16+16).
// Weights pinned in registers via VOLATILE loads (a volatile access must
// execute exactly once where written -> compiler cannot sink the loads into
// the step loop; round-4 VGPR=108 proved the plain loads were being re-issued
// every step). Wave w owns ktiles {4w..4w+3}; its h-MFMAs consume only ranks
// 8w..8w+7 -> per-wave wait-set of 32 flags (8 ranks x 4 waves), one per lane.
// Flags: agent-scope relaxed atomics (round-4-proven visibility; no release
// fences -> no L2 writeback storms). h data: fastp (group verifiably on one
// XCD) -> plain stores meeting in the XCD L2; else agent-relaxed atomics.
template<int LAYER>
__global__ __launch_bounds__(256, 1)
void k_scan(const unsigned short* __restrict__ xin, unsigned short* __restrict__ hex,
            const unsigned short* __restrict__ wp, const float* __restrict__ bias,
            int* __restrict__ flags, int* __restrict__ xmap, float* __restrict__ aux){
  __shared__ __align__(16) float zs[2][4*64*20];   // double-buffered zones
  __shared__ float blds[64];
  int g = blockIdx.x & 7, r = blockIdx.x >> 3;
  int tid = threadIdx.x, w = tid >> 6, lane = tid & 63;

  // weight fragments -> registers (volatile: executed once, stays resident)
  const volatile s16x8* wpv = (const volatile s16x8*)((const s16x8*)wp + (size_t)r*128*64);
  s16x8 B[8][4];
#pragma unroll
  for (int ki = 0; ki < 8; ki++){
    int kt = (ki < 4) ? (4*w + ki) : (12 + 4*w + ki);
#pragma unroll
    for (int n = 0; n < 4; n++)
      B[ki][n] = wpv[((size_t)kt*4 + n)*64 + lane];
  }
  if (tid < 64) blds[tid] = bias[r*64 + tid];

  // ---- XCD uniformity handshake (G16-safe fast path for h data) ----
  int myx;
  asm volatile("s_getreg_b32 %0, hwreg(HW_REG_XCC_ID)" : "=s"(myx));
  if (tid == 0)
    __hip_atomic_store(&xmap[g*32 + r], (myx & 0xff) + 1, __ATOMIC_RELAXED, __HIP_MEMORY_SCOPE_AGENT);
  int xv, hb = 0;
  for (;;){
    xv = __hip_atomic_load(&xmap[g*32 + (lane & 31)], __ATOMIC_RELAXED, __HIP_MEMORY_SCOPE_AGENT);
    if (__all(xv != 0)) break;
    __builtin_amdgcn_s_sleep(2);
    if (++hb > (1<<16)) break;
  }
  int xv0 = __builtin_amdgcn_readfirstlane(xv);
  bool fastp = __all(xv != 0 && xv == xv0) != 0;
  __syncthreads();

  int row = tid & 15, cl = (tid >> 4) & 15;   // gate ownership
  int rw = (lane >> 4)*4, cw = lane & 15;     // MFMA C-frag position
  float c = 0.f, s1 = 0.f, s2 = 0.f;

  // publish constants: thread (row, hcol=r*16+cl) -> frag ushort address
  int lane_c = row + 16*((r & 1)*2 + (cl >> 3));
  size_t du_off = ((((size_t)(g*16 + (r >> 1))*64 + lane_c)*8) + (cl & 7)) >> 1;
  int* myflag = flags + (g*32 + r)*16 + w;
  // per-wave wait-set: rank 8w + (lane>>2)&7, wave lane&3 (lanes 32-63 dup)
  const int* fwp = flags + (g*32 + 8*w + ((lane >> 2) & 7))*16 + (lane & 3);

  const s16x8* xv8 = (const s16x8*)xin;
  const s16x8* hvr = (const s16x8*)hex;
  unsigned int* hvw = (unsigned int*)hex;

  // prefetch x fragments for t=0
  s16x8 xa[4];
  {
    const s16x8* ax = xv8 + (g*16 + 4*w)*64 + lane;
#pragma unroll
    for (int i = 0; i < 4; i++) xa[i] = ax[i*64];
  }

  for (int t = 0; t < T_STEPS; t++){
    f32x4 acc[4];
#pragma unroll
    for (int n = 0; n < 4; n++) acc[n] = (f32x4){0.f,0.f,0.f,0.f};
    // X phase (independent of recurrence)
#pragma unroll
    for (int ki = 0; ki < 4; ki++)
#pragma unroll
      for (int n = 0; n < 4; n++)
        acc[n] = __builtin_amdgcn_mfma_f32_16x16x32_bf16(xa[ki], B[ki][n], acc[n], 0,0,0);
    // prefetch next step's x while waiting
    if (t + 1 < T_STEPS){
      const s16x8* ax = xv8 + (size_t)(t+1)*TS8 + (g*16 + 4*w)*64 + lane;
#pragma unroll
      for (int i = 0; i < 4; i++) xa[i] = ax[i*64];
    }
    if (t > 0){
      int bail = 0;
      for (;;){
        int f = __hip_atomic_load(fwp, __ATOMIC_RELAXED, __HIP_MEMORY_SCOPE_AGENT);
        if (__all(f >= t)) break;
        __builtin_amdgcn_s_sleep(2);
        if (++bail > (1<<14)) break;   // bounded safety valve
      }
      asm volatile("" ::: "memory");
      const s16x8* ah = hvr + (size_t)(t-1)*TS8 + (g*16 + 4*w)*64 + lane;
      s16x8 h0 = ah[0], h1 = ah[64], h2 = ah[128], h3 = ah[192];
#pragma unroll
      for (int n = 0; n < 4; n++) acc[n] = __builtin_amdgcn_mfma_f32_16x16x32_bf16(h0, B[4][n], acc[n], 0,0,0);
#pragma unroll
      for (int n = 0; n < 4; n++) acc[n] = __builtin_amdgcn_mfma_f32_16x16x32_bf16(h1, B[5][n], acc[n], 0,0,0);
#pragma unroll
      for (int n = 0; n < 4; n++) acc[n] = __builtin_amdgcn_mfma_f32_16x16x32_bf16(h2, B[6][n], acc[n], 0,0,0);
#pragma unroll
      for (int n = 0; n < 4; n++) acc[n] = __builtin_amdgcn_mfma_f32_16x16x32_bf16(h3, B[7][n], acc[n], 0,0,0);
    }
    // zone stores (double-buffered; pitch 20 floats)
    float* zb = zs[t & 1];
#pragma unroll
    for (int n = 0; n < 4; n++)
      *(f32x4*)&zb[(w*64 + n*16 + cw)*20 + rw] = acc[n];
    __syncthreads();
    // gate math: thread owns (row, hcol = r*16+cl)
    float z4[4];
#pragma unroll
    for (int n = 0; n < 4; n++){
      z4[n] = zb[(      n*16 + cl)*20 + row]
            + zb[( 64 + n*16 + cl)*20 + row]
            + zb[(128 + n*16 + cl)*20 + row]
            + zb[(192 + n*16 + cl)*20 + row]
            + blds[n*16 + cl];
    }
    float gi = fsig(z4[0]), gf = fsig(z4[1]), gg = ftanh(z4[2]), go = fsig(z4[3]);
    c = gf*c + gi*gg;
    float h = go * ftanh(c);
    if (LAYER == 1){ s1 += h; s2 += h*h; }
    if (LAYER == 2 && t == T_STEPS-1) aux[(g*16 + row)*512 + r*16 + cl] = h;
    // publish h: pair (cl, cl+1) into one dword; lanes with even cl store
    unsigned hv = f2bf(h);
    unsigned w32 = hv | (((unsigned)__shfl_down((int)hv, 16)) << 16);
    if (((lane >> 4) & 1) == 0){
      unsigned int* dst = hvw + ((size_t)t*(TS_US/2) + du_off);
      if (fastp) *dst = w32;                     // XCD-local L2 meet point
      else __hip_atomic_store(dst, w32, __ATOMIC_RELAXED, __HIP_MEMORY_SCOPE_AGENT);
    }
    asm volatile("s_waitcnt vmcnt(0)" ::: "memory");   // wave's h stores acked
    if (lane == 0)
      __hip_atomic_store(myflag, t+1, __ATOMIC_RELAXED, __HIP_MEMORY_SCOPE_AGENT);
  }

  if (LAYER == 1){
    s1 += __shfl_down(s1, 8); s2 += __shfl_down(s2, 8);
    s1 += __shfl_down(s1, 4); s2 += __shfl_down(s2, 4);
    s1 += __shfl_down(s1, 2); s2 += __shfl_down(s2, 2);
    s1 += __shfl_down(s1, 1); s2 += __shfl_down(s2, 1);
    if ((tid & 15) == 0){
      int ch = r*16 + cl;
      aux[(ch*8 + g)*2]     = s1;
      aux[(ch*8 + g)*2 + 1] = s2;
    }
  }
}

// ---------- BN2 + dense head ----------
__global__ __launch_bounds__(512)
void k_epilogue(const float* __restrict__ h2,
                const float* __restrict__ g2, const float* __restrict__ be2,
                const float* __restrict__ Wd1, const float* __restrict__ bd1,
                const float* __restrict__ Wd2, const float* __restrict__ bd2,
                float* __restrict__ out){
  __shared__ float mu[512], rs[512], bb[512];
  __shared__ float t16[128*16];
  int tid = threadIdx.x;
  {
    float s = 0.f, q = 0.f;
    for (int r = 0; r < 128; r++){ float v = h2[r*512 + tid]; s += v; q += v*v; }
    float m = s * (1.f/128.f);
    float var = q * (1.f/128.f) - m*m;
    mu[tid] = m;
    rs[tid] = rsqrtf(fmaxf(var,0.f) + 1e-5f) * g2[tid];
    bb[tid] = be2[tid];
  }
  __syncthreads();
  for (int task = tid; task < 2048; task += 512){
    int b = task >> 4, u = task & 15;
    float acc = bd1[u];
    for (int k = 0; k < 512; k++){
      float hn = (h2[b*512 + k] - mu[k]) * rs[k] + bb[k];
      acc += hn * Wd1[k*16 + u];
    }
    t16[task] = tanhf(acc);
  }
  __syncthreads();
  if (tid < 128){
    float acc = bd2[0];
#pragma unroll
    for (int u = 0; u < 16; u++) acc += t16[tid*16 + u] * Wd2[u];
    out[tid] = acc;
  }
}

extern "C" void kernel_launch(void* const* d_in, const int* in_sizes, int n_in,
                              void* d_out, int out_size, void* d_ws, size_t ws_size,
                              hipStream_t stream){
  const float* x    = (const float*)d_in[0];
  const float* Wi1  = (const float*)d_in[1];
  const float* Wh1  = (const float*)d_in[2];
  const float* b1   = (const float*)d_in[3];
  const float* Wi2  = (const float*)d_in[4];
  const float* Wh2  = (const float*)d_in[5];
  const float* b2   = (const float*)d_in[6];
  const float* g1   = (const float*)d_in[7];
  const float* be1  = (const float*)d_in[8];
  const float* g2   = (const float*)d_in[9];
  const float* be2  = (const float*)d_in[10];
  const float* Wd1  = (const float*)d_in[11];
  const float* bd1  = (const float*)d_in[12];
  const float* Wd2  = (const float*)d_in[13];
  const float* bd2  = (const float*)d_in[14];
  float* out = (float*)d_out;

  char* ws = (char*)d_ws;
  size_t off = 0;
  auto alloc = [&](size_t bytes)->void*{
    void* pp = ws + off; off += (bytes + 255) & ~(size_t)255; return pp;
  };
  unsigned short* xpacked = (unsigned short*)alloc((size_t)512*TS_US*2);  // 64 MiB
  unsigned short* S       = (unsigned short*)alloc((size_t)514*TS_US*2);  // 64.25 MiB
  unsigned short* w1p     = (unsigned short*)alloc((size_t)32*128*64*8*2);
  unsigned short* w2p     = (unsigned short*)alloc((size_t)32*128*64*8*2);
  float* bias1  = (float*)alloc(2048*4);
  float* bias2  = (float*)alloc(2048*4);
  float* stats1 = (float*)alloc((size_t)512*8*2*4);
  int*   flags1 = (int*)alloc(4096*4);
  int*   flags2 = (int*)alloc(4096*4);
  int*   xmap1  = (int*)alloc(1024);
  int*   xmap2  = (int*)alloc(1024);
  float* h2last = (float*)alloc((size_t)128*512*4);

  if (off > ws_size){
    k_sentinel<<<1, 256, 0, stream>>>(out, out_size, (float)(ws_size >> 20));
    return;
  }

  unsigned short* S2 = S + (size_t)2*TS_US;

  k_reset<<<1, 1024, 0, stream>>>(flags1, flags2, xmap1, xmap2);
  k_pack_x<<<4096, 256, 0, stream>>>(x, xpacked);
  k_pack_w1<<<32, 256, 0, stream>>>(Wi1, Wh1, b1, w1p, bias1);
  k_scan<1><<<256, 256, 0, stream>>>(xpacked, S2, w1p, bias1, flags1, xmap1, stats1);
  k_fold2<<<32, 256, 0, stream>>>(Wi2, Wh2, b2, g1, be1, stats1, w2p, bias2);
  k_scan<2><<<256, 256, 0, stream>>>(S2, xpacked, w2p, bias2, flags2, xmap2, h2last);
  k_epilogue<<<1, 512, 0, stream>>>(h2last, g2, be2, Wd1, bd1, Wd2, bd2, out);
}